// Round 5
// baseline (15003.011 us; speedup 1.0000x reference)
//
#include <hip/hip_runtime.h>
#include <cstddef>

#define HID   512
#define G4    2048   // 4*HID
#define NB    32     // batch
#define SEQL  1024
#define INPD  512
#define NBLK  128    // persistent blocks: block j owns hidden units [4j, 4j+4)
#define TPB   512

__device__ __forceinline__ float sigm(float x) {
    return 1.0f / (1.0f + __expf(-x));
}
__device__ __forceinline__ float tanh_fast(float x) {
    float e = __expf(-2.0f * fabsf(x));
    float t = (1.0f - e) / (1.0f + e);
    return copysignf(t, x);
}

// x_proj chunk GEMM: xbuf[m][n] = sum_k inputs[row(m)][k] * w_ih[n][k] + bih[n] + bhh[n]
__global__ __launch_bounds__(256) void xproj_gemm(const float* __restrict__ x,
                                                  const float* __restrict__ wih,
                                                  const float* __restrict__ bih,
                                                  const float* __restrict__ bhh,
                                                  float* __restrict__ xbuf,
                                                  int chunk, int SC) {
    __shared__ float As[16][68];  // [k][m_local]
    __shared__ float Bs[16][68];  // [k][n_local]
    const int m0 = blockIdx.x * 64;
    const int n0 = blockIdx.y * 64;
    const int tid = threadIdx.x;
    const int tx = tid % 16;       // n-dir
    const int ty = tid / 16;       // m-dir
    const int lr  = tid / 4;       // load row 0..63
    const int lc4 = tid % 4;       // which float4 of 16 k's

    float acc[4][4] = {};

    const int m = m0 + lr;
    const int b  = m / SC;
    const int tl = m % SC;
    const float* arow_base = x + ((size_t)b * SEQL + (size_t)chunk * SC + tl) * INPD + lc4 * 4;
    const float* brow_base = wih + (size_t)(n0 + lr) * INPD + lc4 * 4;

    for (int k0 = 0; k0 < 512; k0 += 16) {
        float4 a4 = *(const float4*)(arow_base + k0);
        float4 b4 = *(const float4*)(brow_base + k0);
        As[lc4 * 4 + 0][lr] = a4.x;
        As[lc4 * 4 + 1][lr] = a4.y;
        As[lc4 * 4 + 2][lr] = a4.z;
        As[lc4 * 4 + 3][lr] = a4.w;
        Bs[lc4 * 4 + 0][lr] = b4.x;
        Bs[lc4 * 4 + 1][lr] = b4.y;
        Bs[lc4 * 4 + 2][lr] = b4.z;
        Bs[lc4 * 4 + 3][lr] = b4.w;
        __syncthreads();
        #pragma unroll
        for (int kk = 0; kk < 16; ++kk) {
            float4 av = *(const float4*)&As[kk][ty * 4];
            float4 bv = *(const float4*)&Bs[kk][tx * 4];
            float a[4] = {av.x, av.y, av.z, av.w};
            float bb[4] = {bv.x, bv.y, bv.z, bv.w};
            #pragma unroll
            for (int i = 0; i < 4; ++i)
                #pragma unroll
                for (int j = 0; j < 4; ++j)
                    acc[i][j] = fmaf(a[i], bb[j], acc[i][j]);
        }
        __syncthreads();
    }

    #pragma unroll
    for (int i = 0; i < 4; ++i) {
        int mo = m0 + ty * 4 + i;
        float* orow = xbuf + (size_t)mo * G4;
        #pragma unroll
        for (int j = 0; j < 4; ++j) {
            int n = n0 + tx * 4 + j;
            orow[n] = acc[i][j] + bih[n] + bhh[n];
        }
    }
}

// Persistent recurrence. 128 blocks x 512 threads; block j owns hidden units
// [4j,4j+4) => 16 gate rows x 32 batches.
// Phase A: 4x4 register tile per thread: thread (r4,b4,kc) computes rows
// 4r4..4r4+3 x batches {b4,b4+8,b4+16,b4+24} over k in [32kc,32kc+32).
// W slice (4 rows x 32 k = 128 f32) lives in VGPRs for the WHOLE sequence.
// h staged to LDS each step; k-partials reduced via padded LDS buffer.
// Cross-block sync: per-block flag lines + per-thread poll (fence-free
// relaxed agent-scope atomics, served at LLC).
__global__ __launch_bounds__(512, 2)
void lstm_persist(const float* __restrict__ whh,   // [2048][512]
                  const float* __restrict__ xbuf,  // [NB*SC][G4]
                  const float* __restrict__ h0,
                  const float* __restrict__ c0,
                  float* __restrict__ hbuf,        // [2][NB][HID]
                  float* __restrict__ cstate,      // [NB][HID]
                  float* __restrict__ out,         // [NB][SEQL][HID]
                  int* __restrict__ flags,         // [NBLK*32], line-padded
                  int step_base, int SC) {
    __shared__ float h_lds[32][516];   // staged h, padded
    __shared__ float part[32][260];    // k-partials [og][kc*16+v], padded, 16B-aligned rows
    __shared__ float gl[32][17];       // gate exchange [b][n]

    const int j  = blockIdx.x;
    const int t  = threadIdx.x;
    const int u0 = 4 * j;

    // ---- compute-role indices
    const int kc = t >> 5;        // 0..15 : k-slice [32kc, 32kc+32)
    const int og = t & 31;        // output-group
    const int b4 = og & 7;        // batch group: batches b4+8*db
    const int r4 = og >> 3;       // row group (= gate type): rows 4r4..4r4+3

    // ---- output-role indices (reduction + gl)
    const int n_o  = t & 15;      // gate row 0..15
    const int b_o  = t >> 4;      // batch 0..31
    const int grow = (n_o >> 2) * HID + u0 + (n_o & 3);   // xbuf gate column
    const int og_o = (n_o >> 2) * 8 + (b_o & 7);
    const int v_o  = (n_o & 3) * 4 + (b_o >> 3);

    // ---- W slice into registers (reused for all SC steps)
    float4 w[4][8];
    #pragma unroll
    for (int dr = 0; dr < 4; ++dr) {
        const float* wrow = whh + (size_t)(r4 * HID + u0 + dr) * INPD + 32 * kc;
        #pragma unroll
        for (int kf = 0; kf < 8; ++kf)
            w[dr][kf] = *(const float4*)(wrow + 4 * kf);
    }

    float c = 0.0f;
    if (t < 128) {
        int u = t >> 5, bb = t & 31;
        c = (step_base == 0 ? c0 : cstate)[bb * HID + u0 + u];
    }

    for (int s = 0; s < SC; ++s) {
        const int g = step_base + s;

        // prefetch this thread's xbuf gate value (used in reduction, 2 barriers later)
        float xg = xbuf[((size_t)b_o * SC + s) * G4 + grow];

        // ---- stage h (64KB) into LDS via LLC-coherent 8B loads
        const float* hsrc = (g == 0) ? h0 : hbuf + (size_t)(g & 1) * NB * HID;
        const unsigned long long* hs8 = (const unsigned long long*)hsrc;
        #pragma unroll
        for (int q = 0; q < 16; ++q) {
            unsigned long long vl = __hip_atomic_load(hs8 + q * 512 + t,
                                                      __ATOMIC_RELAXED,
                                                      __HIP_MEMORY_SCOPE_AGENT);
            int f2 = q * 512 + t;
            int bb = f2 >> 8, k2 = f2 & 255;
            float2 hv;
            __builtin_memcpy(&hv, &vl, 8);
            *(float2*)&h_lds[bb][k2 * 2] = hv;
        }
        __syncthreads();

        // ---- phase A: 4x4 register tile, W from VGPRs, h from LDS
        float acc[4][4] = {};
        const int kbase = 32 * kc;
        #pragma unroll
        for (int kf = 0; kf < 8; ++kf) {
            #pragma unroll
            for (int db = 0; db < 4; ++db) {
                float4 h4 = *(const float4*)&h_lds[b4 + 8 * db][kbase + 4 * kf];
                #pragma unroll
                for (int dr = 0; dr < 4; ++dr) {
                    acc[dr][db] = fmaf(w[dr][kf].x, h4.x, acc[dr][db]);
                    acc[dr][db] = fmaf(w[dr][kf].y, h4.y, acc[dr][db]);
                    acc[dr][db] = fmaf(w[dr][kf].z, h4.z, acc[dr][db]);
                    acc[dr][db] = fmaf(w[dr][kf].w, h4.w, acc[dr][db]);
                }
            }
        }
        // write k-partials
        #pragma unroll
        for (int dr = 0; dr < 4; ++dr) {
            float4 pv = {acc[dr][0], acc[dr][1], acc[dr][2], acc[dr][3]};
            *(float4*)&part[og][kc * 16 + dr * 4] = pv;
        }
        __syncthreads();

        // ---- reduce 16 k-partials per output, add xg
        float sum = xg;
        #pragma unroll
        for (int q = 0; q < 16; ++q)
            sum += part[og_o][q * 16 + v_o];
        gl[b_o][n_o] = sum;
        __syncthreads();

        // ---- phase B: cell update (4 units x 32 batches)
        if (t < 128) {
            int u = t >> 5, bb = t & 31;
            float i_t = sigm(gl[bb][0 + u]);
            float f_t = sigm(gl[bb][4 + u]);
            float g_t = tanh_fast(gl[bb][8 + u]);
            float o_t = sigm(gl[bb][12 + u]);
            c = fmaf(f_t, c, i_t * g_t);
            float hnew = o_t * tanh_fast(c);
            int col = u0 + u;
            __hip_atomic_store(&hbuf[(size_t)((g + 1) & 1) * NB * HID + bb * HID + col],
                               hnew, __ATOMIC_RELAXED, __HIP_MEMORY_SCOPE_AGENT);
            out[((size_t)bb * SEQL + g) * HID + col] = hnew;
        }
        __syncthreads();   // drains vmcnt per wave => h stores acked at LLC

        // ---- arrive: own flag on its own 128B line (parallel, no contention)
        if (t == 0)
            __hip_atomic_store(&flags[j * 32], g + 1,
                               __ATOMIC_RELAXED, __HIP_MEMORY_SCOPE_AGENT);
        // ---- wait: thread t polls flag t (128 independent lines)
        if (t < NBLK) {
            while (__hip_atomic_load(&flags[t * 32], __ATOMIC_RELAXED,
                                     __HIP_MEMORY_SCOPE_AGENT) < g + 1)
                __builtin_amdgcn_s_sleep(1);
        }
        __syncthreads();
    }

    if (t < 128) {
        int u = t >> 5, bb = t & 31;
        cstate[bb * HID + u0 + u] = c;
    }
}

__global__ __launch_bounds__(256) void finalize(const float* __restrict__ hfin,
                                                const float* __restrict__ cs,
                                                float* __restrict__ out) {
    int i = blockIdx.x * blockDim.x + threadIdx.x;
    size_t base = (size_t)NB * SEQL * HID;
    if (i < NB * HID) {
        out[base + i] = hfin[i];
        out[base + NB * HID + i] = cs[i];
    }
}

extern "C" void kernel_launch(void* const* d_in, const int* in_sizes, int n_in,
                              void* d_out, int out_size, void* d_ws, size_t ws_size,
                              hipStream_t stream) {
    const float* x   = (const float*)d_in[0];
    const float* h0  = (const float*)d_in[1];
    const float* c0  = (const float*)d_in[2];
    const float* wih = (const float*)d_in[3];
    const float* whh = (const float*)d_in[4];
    const float* bih = (const float*)d_in[5];
    const float* bhh = (const float*)d_in[6];
    float* out = (float*)d_out;

    char* ws = (char*)d_ws;
    int*   flags  = (int*)ws;                        // 16 KB (128 flags, line-padded)
    float* hbuf   = (float*)(ws + 16384);            // 2 * 64 KB
    float* cstate = hbuf + 2 * NB * HID;             // 64 KB
    float* xbuf   = cstate + NB * HID;

    size_t fixed = 16384 + (size_t)3 * NB * HID * sizeof(float);
    int SC = SEQL;                                    // prefer one persistent launch
    while (SC > 64 && fixed + (size_t)NB * SC * G4 * sizeof(float) > ws_size) SC >>= 1;

    hipMemsetAsync(flags, 0, 16384, stream);

    int nchunks = SEQL / SC;
    for (int ch = 0; ch < nchunks; ++ch) {
        dim3 grd(NB * SC / 64, G4 / 64);
        xproj_gemm<<<grd, 256, 0, stream>>>(x, wih, bih, bhh, xbuf, ch, SC);
        lstm_persist<<<NBLK, TPB, 0, stream>>>(whh, xbuf, h0, c0, hbuf, cstate, out,
                                               flags, ch * SC, SC);
    }

    // total steps = 1024 (even) -> final h parity is buffer 0
    finalize<<<(NB * HID + 255) / 256, 256, 0, stream>>>(hbuf, cstate, out);
}

// Round 6
// 9361.389 us; speedup vs baseline: 1.6026x; 1.6026x over previous
//
#include <hip/hip_runtime.h>
#include <cstddef>

#define HID   512
#define G4    2048   // 4*HID
#define NB    32     // batch
#define SEQL  1024
#define INPD  512
#define NBLK  128    // persistent blocks: block j owns hidden units [4j, 4j+4)
#define TPB   512

__device__ __forceinline__ float sigm(float x) {
    return 1.0f / (1.0f + __expf(-x));
}
__device__ __forceinline__ float tanh_fast(float x) {
    float e = __expf(-2.0f * fabsf(x));
    float t = (1.0f - e) / (1.0f + e);
    return copysignf(t, x);
}

// Permuted gate index: g' = j*16 + type*4 + uu  (block j's 16 gates contiguous)
// orig W row for g':  type*HID + (g'>>4)*4 + uu,  type=(g'&15)>>2, uu=g'&3.
__device__ __forceinline__ int orig_gate(int gp) {
    int r = gp & 15;
    return (r >> 2) * HID + (gp >> 4) * 4 + (r & 3);
}

// x_proj chunk GEMM with PERMUTED output columns:
// xbuf[m][g'] = sum_k inputs[row(m)][k] * w_ih[orig(g')][k] + bih[orig] + bhh[orig]
__global__ __launch_bounds__(256) void xproj_gemm(const float* __restrict__ x,
                                                  const float* __restrict__ wih,
                                                  const float* __restrict__ bih,
                                                  const float* __restrict__ bhh,
                                                  float* __restrict__ xbuf,
                                                  int chunk, int SC) {
    __shared__ float As[16][68];  // [k][m_local]
    __shared__ float Bs[16][68];  // [k][n_local]
    const int m0 = blockIdx.x * 64;
    const int n0 = blockIdx.y * 64;
    const int tid = threadIdx.x;
    const int tx = tid % 16;       // n-dir
    const int ty = tid / 16;       // m-dir
    const int lr  = tid / 4;       // load row 0..63
    const int lc4 = tid % 4;       // which float4 of 16 k's

    float acc[4][4] = {};

    const int m = m0 + lr;
    const int b  = m / SC;
    const int tl = m % SC;
    const float* arow_base = x + ((size_t)b * SEQL + (size_t)chunk * SC + tl) * INPD + lc4 * 4;
    const float* brow_base = wih + (size_t)orig_gate(n0 + lr) * INPD + lc4 * 4;

    for (int k0 = 0; k0 < 512; k0 += 16) {
        float4 a4 = *(const float4*)(arow_base + k0);
        float4 b4 = *(const float4*)(brow_base + k0);
        As[lc4 * 4 + 0][lr] = a4.x;
        As[lc4 * 4 + 1][lr] = a4.y;
        As[lc4 * 4 + 2][lr] = a4.z;
        As[lc4 * 4 + 3][lr] = a4.w;
        Bs[lc4 * 4 + 0][lr] = b4.x;
        Bs[lc4 * 4 + 1][lr] = b4.y;
        Bs[lc4 * 4 + 2][lr] = b4.z;
        Bs[lc4 * 4 + 3][lr] = b4.w;
        __syncthreads();
        #pragma unroll
        for (int kk = 0; kk < 16; ++kk) {
            float4 av = *(const float4*)&As[kk][ty * 4];
            float4 bv = *(const float4*)&Bs[kk][tx * 4];
            float a[4] = {av.x, av.y, av.z, av.w};
            float bb[4] = {bv.x, bv.y, bv.z, bv.w};
            #pragma unroll
            for (int i = 0; i < 4; ++i)
                #pragma unroll
                for (int jj = 0; jj < 4; ++jj)
                    acc[i][jj] = fmaf(a[i], bb[jj], acc[i][jj]);
        }
        __syncthreads();
    }

    #pragma unroll
    for (int i = 0; i < 4; ++i) {
        int mo = m0 + ty * 4 + i;
        float* orow = xbuf + (size_t)mo * G4;
        #pragma unroll
        for (int jj = 0; jj < 4; ++jj) {
            int n = n0 + tx * 4 + jj;
            int og = orig_gate(n);
            orow[n] = acc[i][jj] + bih[og] + bhh[og];
        }
    }
}

// Persistent recurrence. 128 blocks x 512 threads; block j owns hidden units
// [4j,4j+4) => 16 gate rows x 32 batches.
// Phase A: 4x4 register tile: thread (kc, og) with r4=og>>3 (gate type),
// b4=og&7 computes rows (r4, dr=0..3) x batches (b4+8db) over k in [32kc,32kc+32).
// W slice (128 f32) in VGPRs for the WHOLE sequence (launch_bounds(512,1)
// => 256-VGPR budget, no spill).
// Partials: part[kc*16+v][og], og-stride 33 -> exactly 2 lanes/bank on both
// the 16 scalar writes and 16 scalar reduce reads (conflict-free).
// Cross-block sync: per-block flag lines, fence-free relaxed agent atomics.
__global__ __launch_bounds__(512, 1)
void lstm_persist(const float* __restrict__ whh,   // [2048][512]
                  const float* __restrict__ xbuf,  // [NB*SC][G4] permuted cols
                  const float* __restrict__ h0,
                  const float* __restrict__ c0,
                  float* __restrict__ hbuf,        // [2][NB][HID]
                  float* __restrict__ cstate,      // [NB][HID]
                  float* __restrict__ out,         // [NB][SEQL][HID]
                  int* __restrict__ flags,         // [NBLK*32], line-padded
                  int step_base, int SC) {
    __shared__ float h_lds[32][516];     // staged h
    __shared__ float part[256][33];      // [kc*16+v][og]
    __shared__ float gl[32][17];         // gate exchange [b][local gate r]

    const int j  = blockIdx.x;
    const int t  = threadIdx.x;
    const int u0 = 4 * j;

    // ---- compute-role indices
    const int kc = t >> 5;        // 0..15 : k-slice [32kc, 32kc+32)
    const int og = t & 31;
    const int b4 = og & 7;        // batches b4+8*db
    const int r4 = og >> 3;       // gate type, rows (r4, dr)

    // ---- reduce-role: lane t reduces output (og_r = t&31, v_r = t>>5)
    const int og_r = t & 31;
    const int v_r  = t >> 5;                      // 0..15
    const int r_r  = (og_r >> 3) * 4 + (v_r >> 2);  // local gate row 0..15
    const int b_r  = (og_r & 7) + 8 * (v_r & 3);    // batch 0..31

    // ---- W slice into registers (reused for all SC steps)
    float4 w[4][8];
    #pragma unroll
    for (int dr = 0; dr < 4; ++dr) {
        const float* wrow = whh + (size_t)(r4 * HID + u0 + dr) * INPD + 32 * kc;
        #pragma unroll
        for (int kf = 0; kf < 8; ++kf)
            w[dr][kf] = *(const float4*)(wrow + 4 * kf);
    }

    float c = 0.0f;
    if (t < 128) {
        int u = t >> 5, bb = t & 31;
        c = (step_base == 0 ? c0 : cstate)[bb * HID + u0 + u];
    }

    for (int s = 0; s < SC; ++s) {
        const int g = step_base + s;

        // prefetch this lane's xg (coalesced: block j's 16 gates contiguous)
        float xg = xbuf[((size_t)b_r * SC + s) * G4 + 16 * j + r_r];

        // ---- stage h (64KB) into LDS via LLC-coherent 8B loads
        const float* hsrc = (g == 0) ? h0 : hbuf + (size_t)(g & 1) * NB * HID;
        const unsigned long long* hs8 = (const unsigned long long*)hsrc;
        #pragma unroll
        for (int q = 0; q < 16; ++q) {
            unsigned long long vl = __hip_atomic_load(hs8 + q * 512 + t,
                                                      __ATOMIC_RELAXED,
                                                      __HIP_MEMORY_SCOPE_AGENT);
            int f2 = q * 512 + t;
            int bb = f2 >> 8, k2 = f2 & 255;
            float2 hv;
            __builtin_memcpy(&hv, &vl, 8);
            *(float2*)&h_lds[bb][k2 * 2] = hv;
        }
        __syncthreads();

        // ---- phase A: 4x4 register tile, W from VGPRs, h from LDS (32 b128 reads)
        float acc[4][4] = {};
        const int kbase = 32 * kc;
        #pragma unroll
        for (int kf = 0; kf < 8; ++kf) {
            #pragma unroll
            for (int db = 0; db < 4; ++db) {
                float4 h4 = *(const float4*)&h_lds[b4 + 8 * db][kbase + 4 * kf];
                #pragma unroll
                for (int dr = 0; dr < 4; ++dr) {
                    acc[dr][db] = fmaf(w[dr][kf].x, h4.x, acc[dr][db]);
                    acc[dr][db] = fmaf(w[dr][kf].y, h4.y, acc[dr][db]);
                    acc[dr][db] = fmaf(w[dr][kf].z, h4.z, acc[dr][db]);
                    acc[dr][db] = fmaf(w[dr][kf].w, h4.w, acc[dr][db]);
                }
            }
        }
        // ---- write k-partials: v = dr*4+db, 16 conflict-free scalar stores
        #pragma unroll
        for (int v = 0; v < 16; ++v)
            part[kc * 16 + v][og] = acc[v >> 2][v & 3];
        __syncthreads();

        // ---- reduce 16 k-partials (conflict-free scalar reads), add xg
        float sum = xg;
        #pragma unroll
        for (int q = 0; q < 16; ++q)
            sum += part[q * 16 + v_r][og_r];
        gl[b_r][r_r] = sum;
        __syncthreads();

        // ---- phase B: cell update (4 units x 32 batches)
        if (t < 128) {
            int u = t >> 5, bb = t & 31;
            float i_t = sigm(gl[bb][0 + u]);
            float f_t = sigm(gl[bb][4 + u]);
            float g_t = tanh_fast(gl[bb][8 + u]);
            float o_t = sigm(gl[bb][12 + u]);
            c = fmaf(f_t, c, i_t * g_t);
            float hnew = o_t * tanh_fast(c);
            int col = u0 + u;
            __hip_atomic_store(&hbuf[(size_t)((g + 1) & 1) * NB * HID + bb * HID + col],
                               hnew, __ATOMIC_RELAXED, __HIP_MEMORY_SCOPE_AGENT);
            out[((size_t)bb * SEQL + g) * HID + col] = hnew;
        }
        __syncthreads();   // drains vmcnt per wave => h stores acked at LLC

        // ---- arrive: own flag on its own 128B line
        if (t == 0)
            __hip_atomic_store(&flags[j * 32], g + 1,
                               __ATOMIC_RELAXED, __HIP_MEMORY_SCOPE_AGENT);
        // ---- wait: thread t polls flag t (128 independent lines)
        if (t < NBLK) {
            while (__hip_atomic_load(&flags[t * 32], __ATOMIC_RELAXED,
                                     __HIP_MEMORY_SCOPE_AGENT) < g + 1)
                __builtin_amdgcn_s_sleep(1);
        }
        __syncthreads();
    }

    if (t < 128) {
        int u = t >> 5, bb = t & 31;
        cstate[bb * HID + u0 + u] = c;
    }
}

__global__ __launch_bounds__(256) void finalize(const float* __restrict__ hfin,
                                                const float* __restrict__ cs,
                                                float* __restrict__ out) {
    int i = blockIdx.x * blockDim.x + threadIdx.x;
    size_t base = (size_t)NB * SEQL * HID;
    if (i < NB * HID) {
        out[base + i] = hfin[i];
        out[base + NB * HID + i] = cs[i];
    }
}

extern "C" void kernel_launch(void* const* d_in, const int* in_sizes, int n_in,
                              void* d_out, int out_size, void* d_ws, size_t ws_size,
                              hipStream_t stream) {
    const float* x   = (const float*)d_in[0];
    const float* h0  = (const float*)d_in[1];
    const float* c0  = (const float*)d_in[2];
    const float* wih = (const float*)d_in[3];
    const float* whh = (const float*)d_in[4];
    const float* bih = (const float*)d_in[5];
    const float* bhh = (const float*)d_in[6];
    float* out = (float*)d_out;

    char* ws = (char*)d_ws;
    int*   flags  = (int*)ws;                        // 16 KB (128 flags, line-padded)
    float* hbuf   = (float*)(ws + 16384);            // 2 * 64 KB
    float* cstate = hbuf + 2 * NB * HID;             // 64 KB
    float* xbuf   = cstate + NB * HID;

    size_t fixed = 16384 + (size_t)3 * NB * HID * sizeof(float);
    int SC = SEQL;                                    // prefer one persistent launch
    while (SC > 64 && fixed + (size_t)NB * SC * G4 * sizeof(float) > ws_size) SC >>= 1;

    hipMemsetAsync(flags, 0, 16384, stream);

    int nchunks = SEQL / SC;
    for (int ch = 0; ch < nchunks; ++ch) {
        dim3 grd(NB * SC / 64, G4 / 64);
        xproj_gemm<<<grd, 256, 0, stream>>>(x, wih, bih, bhh, xbuf, ch, SC);
        lstm_persist<<<NBLK, TPB, 0, stream>>>(whh, xbuf, h0, c0, hbuf, cstate, out,
                                               flags, ch * SC, SC);
    }

    // total steps = 1024 (even) -> final h parity is buffer 0
    finalize<<<(NB * HID + 255) / 256, 256, 0, stream>>>(hbuf, cstate, out);
}